// Round 10
// baseline (337.740 us; speedup 1.0000x reference)
//
#include <hip/hip_runtime.h>
#include <hip/hip_bf16.h>

// 2-layer GCN, N=50000, E=800000, D_IN=256, H=256, D_OUT=128.
// Round 13: CSR rows padded to multiples of 8 (pad col entries point at a
// zeroed h-row index N) -> gather loop has NO tail, 16B-aligned col, and
// loads all 8 col indices with ONE u16x8 load; next col vector is
// software-prefetched during the h-load wait (branchless, col has slack).
// Gather blocks are 512 threads (8 waves) to raise resident-wave count.
// Kept: closed-form sorted CSR, dinv folded into GEMM rows, uint16 col,
// chunk-major XCD-pinned h slabs, lane-owns-8-features.

typedef __attribute__((ext_vector_type(8))) short bf16x8;
typedef __attribute__((ext_vector_type(8))) unsigned short u16x8;
typedef __attribute__((ext_vector_type(4))) float f32x4;

__device__ inline float bf2f(unsigned short u) {
    return __uint_as_float(((unsigned)u) << 16);
}
__device__ inline unsigned short f2bf(float f) {
    unsigned x = __float_as_uint(f);
    unsigned r = (x + 0x7fffu + ((x >> 16) & 1u)) >> 16;   // RNE
    return (unsigned short)r;
}

// ---------------- degree / dinv ----------------
__global__ void degree_kernel(const int* __restrict__ dst, unsigned* __restrict__ deg, int E) {
    int e = blockIdx.x * blockDim.x + threadIdx.x;
    if (e < E) atomicAdd(&deg[dst[e]], 1u);
}

__global__ void dinv_kernel(const unsigned* __restrict__ deg, float* __restrict__ dinv, int N) {
    int i = blockIdx.x * blockDim.x + threadIdx.x;
    if (i < N) dinv[i] = rsqrtf((float)(deg[i] + 1u));  // +1 self-loop
}

// ---------------- degree sort (descending) via LDS histograms ------------
// bin = NBIN-1-deg. All nodes in a bin share one degree -> padded rowptr is
// closed-form from the histogram (deg8 = deg rounded up to multiple of 8).
#define NBIN 512

__global__ __launch_bounds__(256) void hist_lds_kernel(const unsigned* __restrict__ deg,
                                                       int* __restrict__ hist, int N) {
    __shared__ int lh[NBIN];
    const int t = threadIdx.x;
#pragma unroll
    for (int i = 0; i < NBIN / 256; i++) lh[t + i * 256] = 0;
    __syncthreads();
    int idx = blockIdx.x * 256 + t;
    if (idx < N) {
        int b = (int)deg[idx]; if (b > NBIN - 1) b = NBIN - 1;
        atomicAdd(&lh[NBIN - 1 - b], 1);
    }
    __syncthreads();
#pragma unroll
    for (int i = 0; i < NBIN / 256; i++) {
        int v = lh[t + i * 256];
        if (v) atomicAdd(&hist[t + i * 256], v);
    }
}

// 1-wave dual scan: node-space base (binstart/bincur) and PADDED edge-space
// base (edgebase, deg8 per row). rowptr[N] = padded total.
__global__ void scan_bins_kernel(const int* __restrict__ hist,
                                 int* __restrict__ binstart,
                                 int* __restrict__ bincur,
                                 int* __restrict__ edgebase,
                                 int* __restrict__ rowptr, int N) {
    const int t = threadIdx.x;      // 64 threads
    int cn = 0, ce = 0;
    for (int b = 0; b < NBIN; b += 64) {
        int i = b + t;
        int cnt = hist[i];
        int d = NBIN - 1 - i;
        int d8 = (d + 7) & ~7;
        int en = cnt * d8;
        int xn = cnt, xe = en;
#pragma unroll
        for (int off = 1; off < 64; off <<= 1) {
            int yn = __shfl_up(xn, off, 64);
            int ye = __shfl_up(xe, off, 64);
            if (t >= off) { xn += yn; xe += ye; }
        }
        binstart[i] = cn + xn - cnt;
        bincur[i]   = cn + xn - cnt;
        edgebase[i] = ce + xe - en;
        cn += __shfl(xn, 63, 64);
        ce += __shfl(xe, 63, 64);
    }
    if (t == 0) rowptr[N] = ce;     // padded E8
}

// fused place: LDS-rank replay + one reservation per nonzero bin, then write
// perm/rank/rowptr/cursor and the row's PAD col entries (index N -> zero row).
__global__ __launch_bounds__(256) void place_fused_kernel(
    const unsigned* __restrict__ deg,
    int* __restrict__ bincur,
    const int* __restrict__ binstart,
    const int* __restrict__ edgebase,
    int* __restrict__ perm, int* __restrict__ rankv,
    int* __restrict__ rowptr, int* __restrict__ cursor,
    unsigned short* __restrict__ col, int N) {
    __shared__ int lh[NBIN];
    __shared__ int base[NBIN];
    const int t = threadIdx.x;
#pragma unroll
    for (int i = 0; i < NBIN / 256; i++) lh[t + i * 256] = 0;
    __syncthreads();
    int idx = blockIdx.x * 256 + t;
    int bin = 0, lrank = 0;
    if (idx < N) {
        int b = (int)deg[idx]; if (b > NBIN - 1) b = NBIN - 1;
        bin = NBIN - 1 - b;
        lrank = atomicAdd(&lh[bin], 1);
    }
    __syncthreads();
#pragma unroll
    for (int i = 0; i < NBIN / 256; i++) {
        int v = lh[t + i * 256];
        if (v) base[t + i * 256] = atomicAdd(&bincur[t + i * 256], v);
    }
    __syncthreads();
    if (idx < N) {
        int pos = base[bin] + lrank;
        int d = NBIN - 1 - bin;
        int d8 = (d + 7) & ~7;
        int rp = edgebase[bin] + (pos - binstart[bin]) * d8;
        perm[pos] = idx;
        rankv[idx] = pos;
        rowptr[pos] = rp;
        cursor[pos] = rp;
        for (int k = d; k < d8; k++) col[rp + k] = (unsigned short)N;  // pad
    }
}

// ---------------- CSR fill (sorted rows, uint16 col) ----------------
__global__ __launch_bounds__(256) void fill_kernel(const int* __restrict__ src,
                                                   const int* __restrict__ dst,
                                                   const int* __restrict__ rank,
                                                   int* __restrict__ cursor,
                                                   unsigned short* __restrict__ col, int E) {
    int e = blockIdx.x * blockDim.x + threadIdx.x;
    if (e < E) {
        int d = dst[e];
        int pos = atomicAdd(&cursor[rank[d]], 1);
        col[pos] = (unsigned short)src[e];
    }
}

// ---------------- fp32 -> bf16 convert with dinv row-scale (x) -----------
__global__ __launch_bounds__(256) void convert_x_kernel(const float* __restrict__ in,
                                                        const float* __restrict__ dinv,
                                                        unsigned short* __restrict__ out,
                                                        long n4, int ld4) {
    long i = (long)blockIdx.x * blockDim.x + threadIdx.x;
    if (i < n4) {
        float ds = dinv[i / ld4];       // row scale
        float4 v = ((const float4*)in)[i];
        ushort4 o;
        o.x = f2bf(v.x * ds); o.y = f2bf(v.y * ds);
        o.z = f2bf(v.z * ds); o.w = f2bf(v.w * ds);
        ((ushort4*)out)[i] = o;
    }
}

// ---------------- fp32 W[K][Nw] -> bf16 WT[Nw][K] ----------------
__global__ __launch_bounds__(256) void convert_wt_kernel(const float* __restrict__ W,
                                                         unsigned short* __restrict__ WT,
                                                         int K, int Nw) {
    int id = blockIdx.x * blockDim.x + threadIdx.x;
    if (id < K * Nw) {
        int k = id / Nw;
        int n = id % Nw;
        WT[(long)n * K + k] = f2bf(W[id]);
    }
}

// ---------------- zero the pad row (index N) of each chunk slab ----------
__global__ void zero_pad_kernel(unsigned short* __restrict__ h1,
                                unsigned short* __restrict__ h2, int Np1) {
    int t = threadIdx.x;
    if (t < 8 * 32) {
        int c = t >> 5, f = t & 31;
        h1[((size_t)c * Np1 + (Np1 - 1)) * 32 + f] = 0;
    } else if (t < 12 * 32) {
        int q = t - 256;
        int c = q >> 5, f = q & 31;
        h2[((size_t)c * Np1 + (Np1 - 1)) * 32 + f] = 0;
    }
}

// ---------------- bf16 MFMA GEMM: C = A[M,K] * BT[Nc,K]^T, chunk-major C --
// C written as [Nc/CH][ldm][CH] bf16 (ldm = N+1; row N left for pad zeros).
#define GBM 128
#define GBN 128
#define GBK 64
template <int CH>
__global__ __launch_bounds__(256) void gemm_bf16(const unsigned short* __restrict__ A,
                                                 const unsigned short* __restrict__ BT,
                                                 unsigned short* __restrict__ C,
                                                 int M, int Nc, int K, int ldm) {
    __shared__ __align__(16) unsigned short As[GBM * GBK];
    __shared__ __align__(16) unsigned short Bs[GBN * GBK];
    const int t = threadIdx.x;
    const int lane = t & 63;
    const int w = t >> 6;
    const int row0 = blockIdx.x * GBM;
    const int col0 = blockIdx.y * GBN;
    const int rb = (w >> 1) * 64;
    const int cb = (w & 1) * 64;

    f32x4 acc[4][4] = {};

    for (int kb = 0; kb < K; kb += GBK) {
#pragma unroll
        for (int i = 0; i < 4; i++) {
            int p = i * 256 + t;
            int row = p >> 3;
            int slot = p & 7;
            int chunk = slot ^ (row & 7);
            int grow = row0 + row;
            if (grow >= M) grow = M - 1;          // clamp; garbage rows never stored
            const unsigned short* src = A + (size_t)grow * K + kb + chunk * 8;
            __builtin_amdgcn_global_load_lds(
                (const __attribute__((address_space(1))) void*)src,
                (__attribute__((address_space(3))) void*)&As[p * 8], 16, 0, 0);
        }
#pragma unroll
        for (int i = 0; i < 4; i++) {
            int p = i * 256 + t;
            int row = p >> 3;
            int slot = p & 7;
            int chunk = slot ^ (row & 7);
            const unsigned short* src = BT + (size_t)(col0 + row) * K + kb + chunk * 8;
            __builtin_amdgcn_global_load_lds(
                (const __attribute__((address_space(1))) void*)src,
                (__attribute__((address_space(3))) void*)&Bs[p * 8], 16, 0, 0);
        }
        asm volatile("s_waitcnt vmcnt(0)" ::: "memory");
        __syncthreads();

#pragma unroll
        for (int ks = 0; ks < 2; ks++) {
            int kq = ks * 4 + (lane >> 4);
            int rsel = lane & 15;
            bf16x8 af[4], bfr[4];
#pragma unroll
            for (int mt = 0; mt < 4; mt++) {
                int m = rb + mt * 16 + rsel;
                int slot = kq ^ (m & 7);
                af[mt] = *(const bf16x8*)&As[m * GBK + slot * 8];
            }
#pragma unroll
            for (int nt = 0; nt < 4; nt++) {
                int n = cb + nt * 16 + rsel;
                int slot = kq ^ (n & 7);
                bfr[nt] = *(const bf16x8*)&Bs[n * GBK + slot * 8];
            }
#pragma unroll
            for (int mt = 0; mt < 4; mt++)
#pragma unroll
                for (int nt = 0; nt < 4; nt++)
                    acc[mt][nt] = __builtin_amdgcn_mfma_f32_16x16x32_bf16(
                        af[mt], bfr[nt], acc[mt][nt], 0, 0, 0);
        }
        __syncthreads();
    }

    // epilogue: chunk-major C[(gcol/CH)*ldm + g][gcol%CH]
#pragma unroll
    for (int mt = 0; mt < 4; mt++) {
#pragma unroll
        for (int nt = 0; nt < 4; nt++) {
            int gcol = col0 + cb + nt * 16 + (lane & 15);
            int c = gcol / CH;
            int fo = gcol % CH;
            int grow0 = row0 + rb + mt * 16 + 4 * (lane >> 4);
#pragma unroll
            for (int r = 0; r < 4; r++) {
                int g = grow0 + r;
                if (g < M)
                    C[((size_t)c * ldm + g) * CH + fo] = f2bf(acc[mt][nt][r]);
            }
        }
    }
}

// ---------------- XCD-pinned chunk-major CSR pull-gather ------------------
// Padded rows: nit = (rowptr[i+1]-rowptr[i])/8 exact, no tail, no
// divergence. Per iteration: ONE aligned u16x8 col load (8 indices) then 8
// independent h-loads; next col vector prefetched during the h wait (col
// has +8 slack so the prefetch is branchless). Pad index N hits the zeroed
// row (L1-resident). 512-thread blocks (8 waves) for more in-flight loads.
template <int CH, int NCH, bool OUT_BF16>
__global__ __launch_bounds__(512) void gather_cm_kernel(
    const unsigned short* __restrict__ h_cm,   // [NCH][Nn+1][CH], row Nn = 0
    const int* __restrict__ rowptr,            // sorted-order padded CSR
    const unsigned short* __restrict__ col,    // uint16 src ids (+pad N)
    const int* __restrict__ perm,
    const float* __restrict__ dinv,
    const float* __restrict__ bias,
    void* __restrict__ out,                    // node-major [N][F]
    int Nn, int F) {
    constexpr int LF = CH / 8;       // lanes per node
    constexpr int NS = 64 / LF;      // node slots per wave
    constexpr int NPB = NS * 8;      // nodes per block (8 waves)
    const int chunk = blockIdx.x % NCH;
    const int g = blockIdx.x / NCH;
    const int w = threadIdx.x >> 6;
    const int lane = threadIdx.x & 63;
    const int fl = lane & (LF - 1);
    const int ns = lane / LF;
    const int idx = g * NPB + w * NS + ns;
    const bool valid = idx < Nn;
    const int cidx = valid ? idx : Nn - 1;
    const int node = perm[cidx];

    const unsigned short* hc = h_cm + (size_t)chunk * (Nn + 1) * CH;
    const int beg = rowptr[cidx];
    const int nit = (rowptr[cidx + 1] - beg) >> 3;
    const float ddst = dinv[node];
    const int fo = fl * 8;           // feature offset within chunk

    float a0[8] = {}, a1[8] = {};
    const unsigned short* cp = col + beg;
    u16x8 cv = *(const u16x8*)cp;
    for (int it = 0; it < nit; ++it) {
        int s0 = cv[0], s1 = cv[1], s2 = cv[2], s3 = cv[3];
        int s4 = cv[4], s5 = cv[5], s6 = cv[6], s7 = cv[7];
        u16x8 u0 = *(const u16x8*)(hc + s0 * CH + fo);
        u16x8 u1 = *(const u16x8*)(hc + s1 * CH + fo);
        u16x8 u2 = *(const u16x8*)(hc + s2 * CH + fo);
        u16x8 u3 = *(const u16x8*)(hc + s3 * CH + fo);
        u16x8 u4 = *(const u16x8*)(hc + s4 * CH + fo);
        u16x8 u5 = *(const u16x8*)(hc + s5 * CH + fo);
        u16x8 u6 = *(const u16x8*)(hc + s6 * CH + fo);
        u16x8 u7 = *(const u16x8*)(hc + s7 * CH + fo);
        cp += 8;
        cv = *(const u16x8*)cp;      // prefetch next (slack-allocated)
#pragma unroll
        for (int j = 0; j < 8; j++) {
            a0[j] += (bf2f(u0[j]) + bf2f(u1[j])) + (bf2f(u2[j]) + bf2f(u3[j]));
            a1[j] += (bf2f(u4[j]) + bf2f(u5[j])) + (bf2f(u6[j]) + bf2f(u7[j]));
        }
    }

    if (valid) {
        u16x8 us = *(const u16x8*)(hc + node * CH + fo);   // self (pre-scaled)
        const int f0g = chunk * CH + fo;
        f32x4 bv0 = *(const f32x4*)(bias + f0g);
        f32x4 bv1 = *(const f32x4*)(bias + f0g + 4);
        float v[8];
#pragma unroll
        for (int j = 0; j < 8; j++) {
            float b = (j < 4) ? bv0[j] : bv1[j - 4];
            float s = (a0[j] + a1[j]) + bf2f(us[j]);
            v[j] = fmaxf(fmaf(s, ddst, b), 0.f);
        }
        if (OUT_BF16) {
            u16x8 o;
#pragma unroll
            for (int j = 0; j < 8; j++) o[j] = f2bf(v[j] * ddst);  // pre-scale for next GEMM
            *(u16x8*)((unsigned short*)out + (size_t)node * F + f0g) = o;
        } else {
            f32x4 o0, o1;
#pragma unroll
            for (int j = 0; j < 4; j++) { o0[j] = v[j]; o1[j] = v[j + 4]; }
            float* op = (float*)out + (size_t)node * F + f0g;
            *(f32x4*)op = o0;
            *(f32x4*)(op + 4) = o1;
        }
    }
}

extern "C" void kernel_launch(void* const* d_in, const int* in_sizes, int n_in,
                              void* d_out, int out_size, void* d_ws, size_t ws_size,
                              hipStream_t stream) {
    const float* x  = (const float*)d_in[0];   // [N, 256]
    const int* ei   = (const int*)d_in[1];     // [2, E] int32
    const float* W1 = (const float*)d_in[2];   // [256, 256]
    const float* b1 = (const float*)d_in[3];   // [256]
    const float* W2 = (const float*)d_in[4];   // [256, 128]
    const float* b2 = (const float*)d_in[5];   // [128]

    const int DIN = 256;
    const int N = in_sizes[0] / DIN;        // 50000
    const int E = in_sizes[1] / 2;          // 800000
    const int H = in_sizes[3];              // 256
    const int DOUT = in_sizes[5];           // 128

    const int* src = ei;
    const int* dst = ei + E;

    // workspace layout (keep col 16B-aligned; all preceding blocks are
    // multiples of 16 bytes for N=50000)
    char* ws = (char*)d_ws;
    unsigned* deg = (unsigned*)ws;                   ws += (size_t)N * 4;
    float* dinv   = (float*)ws;                      ws += (size_t)N * 4;
    int* rowptr   = (int*)ws;                        ws += (size_t)(N + 4) * 4;
    int* hist     = (int*)ws;                        ws += NBIN * 4;
    int* binstart = (int*)ws;                        ws += NBIN * 4;
    int* bincur   = (int*)ws;                        ws += NBIN * 4;
    int* edgebase = (int*)ws;                        ws += NBIN * 4;
    int* perm     = (int*)ws;                        ws += (size_t)N * 4;
    int* rankv    = (int*)ws;                        ws += (size_t)N * 4;
    int* cursor   = (int*)ws;                        ws += (size_t)N * 4;
    unsigned short* col = (unsigned short*)ws;       ws += (size_t)(E + 8 * N + 64) * 2;
    unsigned short* xb  = (unsigned short*)ws;       ws += (size_t)N * DIN * 2;
    unsigned short* w1t = (unsigned short*)ws;       ws += (size_t)DIN * H * 2;
    unsigned short* w2t = (unsigned short*)ws;       ws += (size_t)H * DOUT * 2;
    unsigned short* h1b = (unsigned short*)ws;       ws += (size_t)(N + 1) * H * 2 + 1024;  // [8][N+1][32]
    unsigned short* y1b = (unsigned short*)ws;       ws += (size_t)N * H * 2;               // [N][256]
    unsigned short* h2b = xb;                        // [4][N+1][32]; xb dead after gemm1
    float* outp = (float*)d_out;

    // ---- CSR build + fused LDS degree sort (padded rows) ----
    hipMemsetAsync(deg, 0, (size_t)N * 4, stream);
    hipMemsetAsync(hist, 0, (size_t)NBIN * 4, stream);
    degree_kernel<<<(E + 255) / 256, 256, 0, stream>>>(dst, deg, E);
    dinv_kernel<<<(N + 255) / 256, 256, 0, stream>>>(deg, dinv, N);
    hist_lds_kernel<<<(N + 255) / 256, 256, 0, stream>>>(deg, hist, N);
    scan_bins_kernel<<<1, 64, 0, stream>>>(hist, binstart, bincur, edgebase, rowptr, N);
    place_fused_kernel<<<(N + 255) / 256, 256, 0, stream>>>(
        deg, bincur, binstart, edgebase, perm, rankv, rowptr, cursor, col, N);
    fill_kernel<<<(E + 255) / 256, 256, 0, stream>>>(src, dst, rankv, cursor, col, E);

    // ---- conversions (x rows pre-scaled by dinv) ----
    {
        long n4 = (long)N * DIN / 4;
        convert_x_kernel<<<(int)((n4 + 255) / 256), 256, 0, stream>>>(x, dinv, xb, n4, DIN / 4);
        convert_wt_kernel<<<(DIN * H + 255) / 256, 256, 0, stream>>>(W1, w1t, DIN, H);
        convert_wt_kernel<<<(H * DOUT + 255) / 256, 256, 0, stream>>>(W2, w2t, H, DOUT);
    }

    // ---- layer 1: h1' = (dinv.x) @ W1 (bf16 MFMA, chunk-major CH=32 x 8) --
    {
        dim3 grid((N + GBM - 1) / GBM, H / GBN);
        gemm_bf16<32><<<grid, 256, 0, stream>>>(xb, w1t, h1b, N, H, DIN, N + 1);
    }
    zero_pad_kernel<<<1, 384, 0, stream>>>(h1b, h2b, N + 1);
    {
        constexpr int NPB1 = (64 / (32 / 8)) * 8;   // 128 nodes/block (8 waves)
        gather_cm_kernel<32, 8, true><<<8 * ((N + NPB1 - 1) / NPB1), 512, 0, stream>>>(
            h1b, rowptr, col, perm, dinv, b1, y1b, N, H);
    }

    // ---- layer 2: h2' = y1' @ W2 (bf16 MFMA, chunk-major CH=32 x 4) ----
    {
        dim3 grid((N + GBM - 1) / GBM, DOUT / GBN);
        gemm_bf16<32><<<grid, 256, 0, stream>>>(y1b, w2t, h2b, N, DOUT, H, N + 1);
    }
    {
        constexpr int NPB2 = (64 / (32 / 8)) * 8;   // 128 nodes/block
        gather_cm_kernel<32, 4, false><<<4 * ((N + NPB2 - 1) / NPB2), 512, 0, stream>>>(
            h2b, rowptr, col, perm, dinv, b2, outp, N, DOUT);
    }
}

// Round 11
// 313.454 us; speedup vs baseline: 1.0775x; 1.0775x over previous
//
#include <hip/hip_runtime.h>
#include <hip/hip_bf16.h>

// 2-layer GCN, N=50000, E=800000, D_IN=256, H=256, D_OUT=128.
// Round 14: non-gather cleanup (gather judged near its scattered-L2
// roofline at ~6.8 TB/s of 64B requests). (1) convert_x eliminated: gemm1
// reg-stages A from raw fp32 x with inline dinv row-scale (same swizzled
// LDS layout; B stays global_load_lds). (2) fill uses cursor indexed by
// original node id -> one scattered access per edge (rank[] removed).
// (3) dinv+hist fused; convert_wt(W1,W2)+pad-zero fused; deg|hist adjacent
// -> single memset. 16 -> 11 dispatches. Gather kernels unchanged (r13).

typedef __attribute__((ext_vector_type(8))) short bf16x8;
typedef __attribute__((ext_vector_type(8))) unsigned short u16x8;
typedef __attribute__((ext_vector_type(4))) float f32x4;

__device__ inline float bf2f(unsigned short u) {
    return __uint_as_float(((unsigned)u) << 16);
}
__device__ inline unsigned short f2bf(float f) {
    unsigned x = __float_as_uint(f);
    unsigned r = (x + 0x7fffu + ((x >> 16) & 1u)) >> 16;   // RNE
    return (unsigned short)r;
}

#define NBIN 512

// ---------------- degree ----------------
__global__ void degree_kernel(const int* __restrict__ dst, unsigned* __restrict__ deg, int E) {
    int e = blockIdx.x * blockDim.x + threadIdx.x;
    if (e < E) atomicAdd(&deg[dst[e]], 1u);
}

// ---------------- dinv + LDS histogram (fused) ----------------
__global__ __launch_bounds__(256) void dinv_hist_kernel(const unsigned* __restrict__ deg,
                                                        float* __restrict__ dinv,
                                                        int* __restrict__ hist, int N) {
    __shared__ int lh[NBIN];
    const int t = threadIdx.x;
#pragma unroll
    for (int i = 0; i < NBIN / 256; i++) lh[t + i * 256] = 0;
    __syncthreads();
    int idx = blockIdx.x * 256 + t;
    if (idx < N) {
        unsigned d = deg[idx];
        dinv[idx] = rsqrtf((float)(d + 1u));           // +1 self-loop
        int b = (int)d; if (b > NBIN - 1) b = NBIN - 1;
        atomicAdd(&lh[NBIN - 1 - b], 1);
    }
    __syncthreads();
#pragma unroll
    for (int i = 0; i < NBIN / 256; i++) {
        int v = lh[t + i * 256];
        if (v) atomicAdd(&hist[t + i * 256], v);
    }
}

// 1-wave dual scan: node-space base (binstart/bincur) and PADDED edge-space
// base (edgebase, deg8 per row). rowptr[N] = padded total.
__global__ void scan_bins_kernel(const int* __restrict__ hist,
                                 int* __restrict__ binstart,
                                 int* __restrict__ bincur,
                                 int* __restrict__ edgebase,
                                 int* __restrict__ rowptr, int N) {
    const int t = threadIdx.x;      // 64 threads
    int cn = 0, ce = 0;
    for (int b = 0; b < NBIN; b += 64) {
        int i = b + t;
        int cnt = hist[i];
        int d = NBIN - 1 - i;
        int d8 = (d + 7) & ~7;
        int en = cnt * d8;
        int xn = cnt, xe = en;
#pragma unroll
        for (int off = 1; off < 64; off <<= 1) {
            int yn = __shfl_up(xn, off, 64);
            int ye = __shfl_up(xe, off, 64);
            if (t >= off) { xn += yn; xe += ye; }
        }
        binstart[i] = cn + xn - cnt;
        bincur[i]   = cn + xn - cnt;
        edgebase[i] = ce + xe - en;
        cn += __shfl(xn, 63, 64);
        ce += __shfl(xe, 63, 64);
    }
    if (t == 0) rowptr[N] = ce;     // padded E8
}

// fused place: LDS-rank replay + one reservation per nonzero bin; writes
// perm (by sorted pos), rowptr (by sorted pos), cursor (BY ORIGINAL NODE),
// and the row's PAD col entries (index N -> zero row).
__global__ __launch_bounds__(256) void place_fused_kernel(
    const unsigned* __restrict__ deg,
    int* __restrict__ bincur,
    const int* __restrict__ binstart,
    const int* __restrict__ edgebase,
    int* __restrict__ perm,
    int* __restrict__ rowptr, int* __restrict__ cursor,
    unsigned short* __restrict__ col, int N) {
    __shared__ int lh[NBIN];
    __shared__ int base[NBIN];
    const int t = threadIdx.x;
#pragma unroll
    for (int i = 0; i < NBIN / 256; i++) lh[t + i * 256] = 0;
    __syncthreads();
    int idx = blockIdx.x * 256 + t;
    int bin = 0, lrank = 0;
    if (idx < N) {
        int b = (int)deg[idx]; if (b > NBIN - 1) b = NBIN - 1;
        bin = NBIN - 1 - b;
        lrank = atomicAdd(&lh[bin], 1);
    }
    __syncthreads();
#pragma unroll
    for (int i = 0; i < NBIN / 256; i++) {
        int v = lh[t + i * 256];
        if (v) base[t + i * 256] = atomicAdd(&bincur[t + i * 256], v);
    }
    __syncthreads();
    if (idx < N) {
        int pos = base[bin] + lrank;
        int d = NBIN - 1 - bin;
        int d8 = (d + 7) & ~7;
        int rp = edgebase[bin] + (pos - binstart[bin]) * d8;
        perm[pos] = idx;
        rowptr[pos] = rp;
        cursor[idx] = rp;                                 // by node id
        for (int k = d; k < d8; k++) col[rp + k] = (unsigned short)N;  // pad
    }
}

// ---------------- CSR fill (one scattered access per edge) ----------------
__global__ __launch_bounds__(256) void fill_kernel(const int* __restrict__ src,
                                                   const int* __restrict__ dst,
                                                   int* __restrict__ cursor,
                                                   unsigned short* __restrict__ col, int E) {
    int e = blockIdx.x * blockDim.x + threadIdx.x;
    if (e < E) {
        int d = dst[e];
        int pos = atomicAdd(&cursor[d], 1);
        col[pos] = (unsigned short)src[e];
    }
}

// ------- fused: W1,W2 -> bf16 transposed + zero pad rows of h1b/h2b -------
__global__ __launch_bounds__(256) void convwt_pad_kernel(
    const float* __restrict__ W1, const float* __restrict__ W2,
    unsigned short* __restrict__ w1t, unsigned short* __restrict__ w2t,
    unsigned short* __restrict__ h1b, unsigned short* __restrict__ h2b,
    int DIN, int H, int DOUT, int Np1) {
    int id = blockIdx.x * 256 + threadIdx.x;
    int n1 = DIN * H;
    int n2 = H * DOUT;
    if (id < n1) {
        int k = id / H, n = id % H;
        w1t[(long)n * DIN + k] = f2bf(W1[id]);
    } else if (id < n1 + n2) {
        int q = id - n1;
        int k = q / DOUT, n = q % DOUT;
        w2t[(long)n * H + k] = f2bf(W2[q]);
    } else if (id < n1 + n2 + 384) {
        int q = id - n1 - n2;
        if (q < 256) {                                   // 8 chunks x 32
            int c = q >> 5, f = q & 31;
            h1b[((size_t)c * Np1 + (Np1 - 1)) * 32 + f] = 0;
        } else {                                         // 4 chunks x 32
            int q2 = q - 256;
            int c = q2 >> 5, f = q2 & 31;
            h2b[((size_t)c * Np1 + (Np1 - 1)) * 32 + f] = 0;
        }
    }
}

// ---------------- bf16 MFMA GEMM (A = raw fp32 x, dinv row-scaled) --------
// A staged via registers (float4x2 -> f2bf -> ds_write_b128) into the SAME
// swizzled LDS layout as the gload_lds path; B via global_load_lds.
// C chunk-major [Nc/32][ldm][32].
#define GBM 128
#define GBN 128
#define GBK 64
__global__ __launch_bounds__(256) void gemm_x_bf16(const float* __restrict__ X,
                                                   const float* __restrict__ dinv,
                                                   const unsigned short* __restrict__ BT,
                                                   unsigned short* __restrict__ C,
                                                   int M, int Nc, int K, int ldm) {
    __shared__ __align__(16) unsigned short As[GBM * GBK];
    __shared__ __align__(16) unsigned short Bs[GBN * GBK];
    const int t = threadIdx.x;
    const int lane = t & 63;
    const int w = t >> 6;
    const int row0 = blockIdx.x * GBM;
    const int col0 = blockIdx.y * GBN;
    const int rb = (w >> 1) * 64;
    const int cb = (w & 1) * 64;

    f32x4 acc[4][4] = {};

    for (int kb = 0; kb < K; kb += GBK) {
        // ---- stage A: fp32 -> bf16 reg-staged, dinv row-scale ----
#pragma unroll
        for (int i = 0; i < 4; i++) {
            int p = i * 256 + t;
            int row = p >> 3;
            int slot = p & 7;
            int chunk = slot ^ (row & 7);
            int grow = row0 + row;
            if (grow >= M) grow = M - 1;
            const float* sp = X + (size_t)grow * K + kb + chunk * 8;
            f32x4 v0 = *(const f32x4*)sp;
            f32x4 v1 = *(const f32x4*)(sp + 4);
            float ds = dinv[grow];
            u16x8 o;
#pragma unroll
            for (int j = 0; j < 4; j++) { o[j] = f2bf(v0[j] * ds); o[j + 4] = f2bf(v1[j] * ds); }
            *(u16x8*)&As[p * 8] = o;
        }
        // ---- stage B via global_load_lds ----
#pragma unroll
        for (int i = 0; i < 4; i++) {
            int p = i * 256 + t;
            int row = p >> 3;
            int slot = p & 7;
            int chunk = slot ^ (row & 7);
            const unsigned short* src = BT + (size_t)(col0 + row) * K + kb + chunk * 8;
            __builtin_amdgcn_global_load_lds(
                (const __attribute__((address_space(1))) void*)src,
                (__attribute__((address_space(3))) void*)&Bs[p * 8], 16, 0, 0);
        }
        asm volatile("s_waitcnt vmcnt(0)" ::: "memory");
        __syncthreads();

#pragma unroll
        for (int ks = 0; ks < 2; ks++) {
            int kq = ks * 4 + (lane >> 4);
            int rsel = lane & 15;
            bf16x8 af[4], bfr[4];
#pragma unroll
            for (int mt = 0; mt < 4; mt++) {
                int m = rb + mt * 16 + rsel;
                int slot = kq ^ (m & 7);
                af[mt] = *(const bf16x8*)&As[m * GBK + slot * 8];
            }
#pragma unroll
            for (int nt = 0; nt < 4; nt++) {
                int n = cb + nt * 16 + rsel;
                int slot = kq ^ (n & 7);
                bfr[nt] = *(const bf16x8*)&Bs[n * GBK + slot * 8];
            }
#pragma unroll
            for (int mt = 0; mt < 4; mt++)
#pragma unroll
                for (int nt = 0; nt < 4; nt++)
                    acc[mt][nt] = __builtin_amdgcn_mfma_f32_16x16x32_bf16(
                        af[mt], bfr[nt], acc[mt][nt], 0, 0, 0);
        }
        __syncthreads();
    }

#pragma unroll
    for (int mt = 0; mt < 4; mt++) {
#pragma unroll
        for (int nt = 0; nt < 4; nt++) {
            int gcol = col0 + cb + nt * 16 + (lane & 15);
            int c = gcol >> 5;
            int fo = gcol & 31;
            int grow0 = row0 + rb + mt * 16 + 4 * (lane >> 4);
#pragma unroll
            for (int r = 0; r < 4; r++) {
                int g = grow0 + r;
                if (g < M)
                    C[((size_t)c * ldm + g) * 32 + fo] = f2bf(acc[mt][nt][r]);
            }
        }
    }
}

// ---------------- bf16 MFMA GEMM (bf16 A via global_load_lds) -------------
template <int CH>
__global__ __launch_bounds__(256) void gemm_bf16(const unsigned short* __restrict__ A,
                                                 const unsigned short* __restrict__ BT,
                                                 unsigned short* __restrict__ C,
                                                 int M, int Nc, int K, int ldm) {
    __shared__ __align__(16) unsigned short As[GBM * GBK];
    __shared__ __align__(16) unsigned short Bs[GBN * GBK];
    const int t = threadIdx.x;
    const int lane = t & 63;
    const int w = t >> 6;
    const int row0 = blockIdx.x * GBM;
    const int col0 = blockIdx.y * GBN;
    const int rb = (w >> 1) * 64;
    const int cb = (w & 1) * 64;

    f32x4 acc[4][4] = {};

    for (int kb = 0; kb < K; kb += GBK) {
#pragma unroll
        for (int i = 0; i < 4; i++) {
            int p = i * 256 + t;
            int row = p >> 3;
            int slot = p & 7;
            int chunk = slot ^ (row & 7);
            int grow = row0 + row;
            if (grow >= M) grow = M - 1;
            const unsigned short* src = A + (size_t)grow * K + kb + chunk * 8;
            __builtin_amdgcn_global_load_lds(
                (const __attribute__((address_space(1))) void*)src,
                (__attribute__((address_space(3))) void*)&As[p * 8], 16, 0, 0);
        }
#pragma unroll
        for (int i = 0; i < 4; i++) {
            int p = i * 256 + t;
            int row = p >> 3;
            int slot = p & 7;
            int chunk = slot ^ (row & 7);
            const unsigned short* src = BT + (size_t)(col0 + row) * K + kb + chunk * 8;
            __builtin_amdgcn_global_load_lds(
                (const __attribute__((address_space(1))) void*)src,
                (__attribute__((address_space(3))) void*)&Bs[p * 8], 16, 0, 0);
        }
        asm volatile("s_waitcnt vmcnt(0)" ::: "memory");
        __syncthreads();

#pragma unroll
        for (int ks = 0; ks < 2; ks++) {
            int kq = ks * 4 + (lane >> 4);
            int rsel = lane & 15;
            bf16x8 af[4], bfr[4];
#pragma unroll
            for (int mt = 0; mt < 4; mt++) {
                int m = rb + mt * 16 + rsel;
                int slot = kq ^ (m & 7);
                af[mt] = *(const bf16x8*)&As[m * GBK + slot * 8];
            }
#pragma unroll
            for (int nt = 0; nt < 4; nt++) {
                int n = cb + nt * 16 + rsel;
                int slot = kq ^ (n & 7);
                bfr[nt] = *(const bf16x8*)&Bs[n * GBK + slot * 8];
            }
#pragma unroll
            for (int mt = 0; mt < 4; mt++)
#pragma unroll
                for (int nt = 0; nt < 4; nt++)
                    acc[mt][nt] = __builtin_amdgcn_mfma_f32_16x16x32_bf16(
                        af[mt], bfr[nt], acc[mt][nt], 0, 0, 0);
        }
        __syncthreads();
    }

#pragma unroll
    for (int mt = 0; mt < 4; mt++) {
#pragma unroll
        for (int nt = 0; nt < 4; nt++) {
            int gcol = col0 + cb + nt * 16 + (lane & 15);
            int c = gcol / CH;
            int fo = gcol % CH;
            int grow0 = row0 + rb + mt * 16 + 4 * (lane >> 4);
#pragma unroll
            for (int r = 0; r < 4; r++) {
                int g = grow0 + r;
                if (g < M)
                    C[((size_t)c * ldm + g) * CH + fo] = f2bf(acc[mt][nt][r]);
            }
        }
    }
}

// ---------------- XCD-pinned chunk-major CSR pull-gather (r13) ------------
template <int CH, int NCH, bool OUT_BF16>
__global__ __launch_bounds__(512) void gather_cm_kernel(
    const unsigned short* __restrict__ h_cm,   // [NCH][Nn+1][CH], row Nn = 0
    const int* __restrict__ rowptr,            // sorted-order padded CSR
    const unsigned short* __restrict__ col,    // uint16 src ids (+pad N)
    const int* __restrict__ perm,
    const float* __restrict__ dinv,
    const float* __restrict__ bias,
    void* __restrict__ out,                    // node-major [N][F]
    int Nn, int F) {
    constexpr int LF = CH / 8;       // lanes per node
    constexpr int NS = 64 / LF;      // node slots per wave
    constexpr int NPB = NS * 8;      // nodes per block (8 waves)
    const int chunk = blockIdx.x % NCH;
    const int g = blockIdx.x / NCH;
    const int w = threadIdx.x >> 6;
    const int lane = threadIdx.x & 63;
    const int fl = lane & (LF - 1);
    const int ns = lane / LF;
    const int idx = g * NPB + w * NS + ns;
    const bool valid = idx < Nn;
    const int cidx = valid ? idx : Nn - 1;
    const int node = perm[cidx];

    const unsigned short* hc = h_cm + (size_t)chunk * (Nn + 1) * CH;
    const int beg = rowptr[cidx];
    const int nit = (rowptr[cidx + 1] - beg) >> 3;
    const float ddst = dinv[node];
    const int fo = fl * 8;

    float a0[8] = {}, a1[8] = {};
    const unsigned short* cp = col + beg;
    u16x8 cv = *(const u16x8*)cp;
    for (int it = 0; it < nit; ++it) {
        int s0 = cv[0], s1 = cv[1], s2 = cv[2], s3 = cv[3];
        int s4 = cv[4], s5 = cv[5], s6 = cv[6], s7 = cv[7];
        u16x8 u0 = *(const u16x8*)(hc + s0 * CH + fo);
        u16x8 u1 = *(const u16x8*)(hc + s1 * CH + fo);
        u16x8 u2 = *(const u16x8*)(hc + s2 * CH + fo);
        u16x8 u3 = *(const u16x8*)(hc + s3 * CH + fo);
        u16x8 u4 = *(const u16x8*)(hc + s4 * CH + fo);
        u16x8 u5 = *(const u16x8*)(hc + s5 * CH + fo);
        u16x8 u6 = *(const u16x8*)(hc + s6 * CH + fo);
        u16x8 u7 = *(const u16x8*)(hc + s7 * CH + fo);
        cp += 8;
        cv = *(const u16x8*)cp;      // prefetch next (slack-allocated)
#pragma unroll
        for (int j = 0; j < 8; j++) {
            a0[j] += (bf2f(u0[j]) + bf2f(u1[j])) + (bf2f(u2[j]) + bf2f(u3[j]));
            a1[j] += (bf2f(u4[j]) + bf2f(u5[j])) + (bf2f(u6[j]) + bf2f(u7[j]));
        }
    }

    if (valid) {
        u16x8 us = *(const u16x8*)(hc + node * CH + fo);   // self (pre-scaled)
        const int f0g = chunk * CH + fo;
        f32x4 bv0 = *(const f32x4*)(bias + f0g);
        f32x4 bv1 = *(const f32x4*)(bias + f0g + 4);
        float v[8];
#pragma unroll
        for (int j = 0; j < 8; j++) {
            float b = (j < 4) ? bv0[j] : bv1[j - 4];
            float s = (a0[j] + a1[j]) + bf2f(us[j]);
            v[j] = fmaxf(fmaf(s, ddst, b), 0.f);
        }
        if (OUT_BF16) {
            u16x8 o;
#pragma unroll
            for (int j = 0; j < 8; j++) o[j] = f2bf(v[j] * ddst);  // pre-scale for next GEMM
            *(u16x8*)((unsigned short*)out + (size_t)node * F + f0g) = o;
        } else {
            f32x4 o0, o1;
#pragma unroll
            for (int j = 0; j < 4; j++) { o0[j] = v[j]; o1[j] = v[j + 4]; }
            float* op = (float*)out + (size_t)node * F + f0g;
            *(f32x4*)op = o0;
            *(f32x4*)(op + 4) = o1;
        }
    }
}

extern "C" void kernel_launch(void* const* d_in, const int* in_sizes, int n_in,
                              void* d_out, int out_size, void* d_ws, size_t ws_size,
                              hipStream_t stream) {
    const float* x  = (const float*)d_in[0];   // [N, 256]
    const int* ei   = (const int*)d_in[1];     // [2, E] int32
    const float* W1 = (const float*)d_in[2];   // [256, 256]
    const float* b1 = (const float*)d_in[3];   // [256]
    const float* W2 = (const float*)d_in[4];   // [256, 128]
    const float* b2 = (const float*)d_in[5];   // [128]

    const int DIN = 256;
    const int N = in_sizes[0] / DIN;        // 50000
    const int E = in_sizes[1] / 2;          // 800000
    const int H = in_sizes[3];              // 256
    const int DOUT = in_sizes[5];           // 128

    const int* src = ei;
    const int* dst = ei + E;

    // workspace layout (deg|hist adjacent for single memset; col 16B-aligned)
    char* ws = (char*)d_ws;
    unsigned* deg = (unsigned*)ws;                   ws += (size_t)N * 4;
    int* hist     = (int*)ws;                        ws += NBIN * 4;
    float* dinv   = (float*)ws;                      ws += (size_t)N * 4;
    int* rowptr   = (int*)ws;                        ws += (size_t)(N + 4) * 4;
    int* binstart = (int*)ws;                        ws += NBIN * 4;
    int* bincur   = (int*)ws;                        ws += NBIN * 4;
    int* edgebase = (int*)ws;                        ws += NBIN * 4;
    int* perm     = (int*)ws;                        ws += (size_t)N * 4;
    int* cursor   = (int*)ws;                        ws += (size_t)N * 4;
    unsigned short* col = (unsigned short*)ws;       ws += (size_t)(E + 8 * N + 64) * 2;
    unsigned short* w1t = (unsigned short*)ws;       ws += (size_t)DIN * H * 2;
    unsigned short* w2t = (unsigned short*)ws;       ws += (size_t)H * DOUT * 2;
    unsigned short* h1b = (unsigned short*)ws;       ws += (size_t)(N + 1) * H * 2 + 1024;   // [8][N+1][32]
    unsigned short* y1b = (unsigned short*)ws;       ws += (size_t)N * H * 2;                // [N][256]
    unsigned short* h2b = (unsigned short*)ws;       ws += (size_t)(N + 1) * DOUT * 2 + 1024;// [4][N+1][32]
    float* outp = (float*)d_out;

    // ---- CSR build + fused LDS degree sort (padded rows) ----
    hipMemsetAsync(deg, 0, (size_t)N * 4 + NBIN * 4, stream);   // deg + hist
    degree_kernel<<<(E + 255) / 256, 256, 0, stream>>>(dst, deg, E);
    dinv_hist_kernel<<<(N + 255) / 256, 256, 0, stream>>>(deg, dinv, hist, N);
    scan_bins_kernel<<<1, 64, 0, stream>>>(hist, binstart, bincur, edgebase, rowptr, N);
    place_fused_kernel<<<(N + 255) / 256, 256, 0, stream>>>(
        deg, bincur, binstart, edgebase, perm, rowptr, cursor, col, N);
    fill_kernel<<<(E + 255) / 256, 256, 0, stream>>>(src, dst, cursor, col, E);

    // ---- weights -> bf16 transposed + pad-row zeroing (fused) ----
    {
        int tot = DIN * H + H * DOUT + 384;
        convwt_pad_kernel<<<(tot + 255) / 256, 256, 0, stream>>>(
            W1, W2, w1t, w2t, h1b, h2b, DIN, H, DOUT, N + 1);
    }

    // ---- layer 1: h1' = (dinv.x) @ W1, fp32-A reg-staged GEMM ----
    {
        dim3 grid((N + GBM - 1) / GBM, H / GBN);
        gemm_x_bf16<<<grid, 256, 0, stream>>>(x, dinv, w1t, h1b, N, H, DIN, N + 1);
    }
    {
        constexpr int NPB1 = (64 / (32 / 8)) * 8;   // 128 nodes/block (8 waves)
        gather_cm_kernel<32, 8, true><<<8 * ((N + NPB1 - 1) / NPB1), 512, 0, stream>>>(
            h1b, rowptr, col, perm, dinv, b1, y1b, N, H);
    }

    // ---- layer 2: h2' = y1' @ W2 (bf16 MFMA) ----
    {
        dim3 grid((N + GBM - 1) / GBM, DOUT / GBN);
        gemm_bf16<32><<<grid, 256, 0, stream>>>(y1b, w2t, h2b, N, DOUT, H, N + 1);
    }
    {
        constexpr int NPB2 = (64 / (32 / 8)) * 8;   // 128 nodes/block
        gather_cm_kernel<32, 4, false><<<4 * ((N + NPB2 - 1) / NPB2), 512, 0, stream>>>(
            h2b, rowptr, col, perm, dinv, b2, outp, N, DOUT);
    }
}